// Round 4
// baseline (185.527 us; speedup 1.0000x reference)
//
#include <hip/hip_runtime.h>

// YOLOv7 P3 head (stride 8): B=16, A=3, NC=80, H=W=80.
// Input  (b, a*85, h, w) channel-major fp32.
// Output (b, a*h*w, 85)  fp32: [px,py,pw,ph,conf,cls*80].
//
// Block = (b, a, y-pair): 1920 blocks x 1024 threads.
//   LDS 54.4 KB -> 2 blocks/CU x 16 waves = 32 waves/CU (100% cap).
//   Reads: 640 B contiguous per channel (2 rows); 1 KB per wave-instruction.
//   Output: y-pair tile = 13600 contiguous floats at bid*13600.
// Phase 1a: BATCHED loads into f32x4 v[4] (4 outstanding global_load_dwordx4
//           per thread — R3's VGPR_Count=12 showed loads were serialized).
// Phase 1b: transform -> scalar LDS writes in output order.
// Phase 2:  contiguous LDS float4 reads -> nontemporal 16B stores.

#define A_     3
#define H_     80
#define W_     80
#define CH_    85              // 5 + 80 classes
#define ROWS_  2               // y rows per block
#define TILE_  (CH_ * W_ * ROWS_)   // 13600 floats
#define VEC_   (TILE_ / 4)          // 3400 float4
#define XQ_    (W_ * ROWS_ / 4)     // 40 float4 per channel
#define NBLK_  (16 * A_ * (H_ / ROWS_))  // 1920

typedef float f32x4 __attribute__((ext_vector_type(4)));

__device__ __forceinline__ float fast_sigmoid(float x) {
    return __builtin_amdgcn_rcpf(1.0f + __expf(-x));
}

__global__ __launch_bounds__(1024) void yolo_head_kernel(
    const float* __restrict__ in,
    const float* __restrict__ anchors,
    float* __restrict__ out)
{
    __shared__ float lds[TILE_];

    const int bid = blockIdx.x;          // (b*3 + a)*40 + yp
    const int yp  = bid % (H_ / ROWS_);
    const int ba  = bid / (H_ / ROWS_);  // b*3 + a
    const int a   = ba % A_;
    const int y0  = ROWS_ * yp;

    const float aw = anchors[2 * a];
    const float ah = anchors[2 * a + 1];
    const int   t  = threadIdx.x;

    // in[(ba*85 + ch)*6400 + y0*80 + (0..159)]
    const float* in_base = in + (size_t)(ba * CH_) * (H_ * W_) + y0 * W_;

    // ---- Phase 1a: batched global loads (keep 4 in flight) ----
    f32x4 v[4];
#pragma unroll
    for (int k = 0; k < 4; ++k) {
        int i = k * 1024 + t;            // i = ch*40 + xq
        if (i < VEC_) {
            int ch = i / XQ_;
            int xq = i - ch * XQ_;
            v[k] = *(const f32x4*)(in_base + ch * (H_ * W_) + 4 * xq);
        }
    }

    // ---- Phase 1b: transform -> LDS in output order ----
#pragma unroll
    for (int k = 0; k < 4; ++k) {
        int i = k * 1024 + t;
        if (i < VEC_) {
            int ch = i / XQ_;
            int xq = i - ch * XQ_;
            int yy = xq / 20;            // which of the 2 rows
            int xl = 4 * (xq - 20 * yy); // x within row
            float r[4];
            if (ch >= 4) {
                r[0] = fast_sigmoid(v[k].x);
                r[1] = fast_sigmoid(v[k].y);
                r[2] = fast_sigmoid(v[k].z);
                r[3] = fast_sigmoid(v[k].w);
            } else if (ch == 0) {
                float x0 = (float)xl;
                r[0] = (fast_sigmoid(v[k].x) + x0)        * 8.0f;  // px
                r[1] = (fast_sigmoid(v[k].y) + x0 + 1.0f) * 8.0f;
                r[2] = (fast_sigmoid(v[k].z) + x0 + 2.0f) * 8.0f;
                r[3] = (fast_sigmoid(v[k].w) + x0 + 3.0f) * 8.0f;
            } else if (ch == 1) {
                float fy = (float)(y0 + yy);
                r[0] = (fast_sigmoid(v[k].x) + fy) * 8.0f;         // py
                r[1] = (fast_sigmoid(v[k].y) + fy) * 8.0f;
                r[2] = (fast_sigmoid(v[k].z) + fy) * 8.0f;
                r[3] = (fast_sigmoid(v[k].w) + fy) * 8.0f;
            } else {
                float s = (ch == 2) ? aw : ah;                     // pw / ph
                r[0] = __expf(fminf(fmaxf(v[k].x, -16.0f), 16.0f)) * s;
                r[1] = __expf(fminf(fmaxf(v[k].y, -16.0f), 16.0f)) * s;
                r[2] = __expf(fminf(fmaxf(v[k].z, -16.0f), 16.0f)) * s;
                r[3] = __expf(fminf(fmaxf(v[k].w, -16.0f), 16.0f)) * s;
            }
            // lds[(yy*80 + x)*85 + ch]
            int base = yy * (W_ * CH_) + xl * CH_ + ch;
#pragma unroll
            for (int j = 0; j < 4; ++j)
                lds[base + j * CH_] = r[j];
        }
    }
    __syncthreads();

    // ---- Phase 2: LDS -> out, contiguous 16B nontemporal stores ----
    f32x4*       out4 = (f32x4*)(out + (size_t)bid * TILE_);
    const f32x4* lds4 = (const f32x4*)lds;
#pragma unroll
    for (int k = 0; k < 4; ++k) {
        int c = k * 1024 + t;
        if (c < VEC_) {
            __builtin_nontemporal_store(lds4[c], &out4[c]);
        }
    }
}

extern "C" void kernel_launch(void* const* d_in, const int* in_sizes, int n_in,
                              void* d_out, int out_size, void* d_ws, size_t ws_size,
                              hipStream_t stream) {
    const float* in      = (const float*)d_in[0];   // (16, 255, 80, 80) fp32
    const float* anchors = (const float*)d_in[1];   // (3, 2) fp32
    float*       out     = (float*)d_out;           // (16, 19200, 85) fp32

    yolo_head_kernel<<<NBLK_, 1024, 0, stream>>>(in, anchors, out);
}